// Round 1
// 858.689 us; speedup vs baseline: 1.0816x; 1.0816x over previous
//
#include <hip/hip_runtime.h>
#include <hip/hip_bf16.h>
#include <cstdint>

#define E_EDGES 800000
#define NN 50000

typedef __attribute__((ext_vector_type(8))) short short8;
typedef __attribute__((ext_vector_type(4))) float f32x4;
typedef __attribute__((ext_vector_type(16))) float f32x16;

#define MFMA32(a,b,c) __builtin_amdgcn_mfma_f32_32x32x16_bf16((a),(b),(c),0,0,0)
#define MFMA16(a,b,c) __builtin_amdgcn_mfma_f32_16x16x32_bf16((a),(b),(c),0,0,0)

// ---- workspace layout (bytes) ----
#define OFF_WE1T   0u                          // [128n][192k] bf16
#define OFF_WA1T   49152u                      // [128][192]
#define OFF_WE2T   98304u                      // [64n][128k]
#define OFF_WN1T   114688u                     // [128][128]
#define OFF_WN2T   147456u                     // [64][128]
#define OFF_LOGIT  163840u                     // E f32
#define OFF_SEGMAXU (OFF_LOGIT + E_EDGES*4u)   // N u32   (zeroed)
#define OFF_SEGSUM (OFF_SEGMAXU + NN*4u)       // N f32   (zeroed)
#define OFF_CNTI   (OFF_SEGSUM + NN*4u)        // N i32   (zeroed)
#define OFF_AGG    (OFF_CNTI + NN*4u)          // N*64 f32 UNNORMALIZED Σ ev*uef (zeroed)

__device__ __forceinline__ unsigned short bf16s(float f) {
    unsigned u = __float_as_uint(f);
    u = (u + 0x7FFFu + ((u >> 16) & 1u)) >> 16;
    return (unsigned short)u;
}
__device__ __forceinline__ unsigned fkey(float f) {
    unsigned u = __float_as_uint(f);
    return (u & 0x80000000u) ? ~u : (u | 0x80000000u);
}
__device__ __forceinline__ float funkey(unsigned k) {
    unsigned u = (k & 0x80000000u) ? (k & 0x7FFFFFFFu) : ~k;
    return __uint_as_float(u);
}

// ---- K0: transpose + convert weights to bf16 in ws ----
__global__ void k0_init(const float* __restrict__ We1, const float* __restrict__ Wa1,
                        const float* __restrict__ We2, const float* __restrict__ Wn1,
                        const float* __restrict__ Wn2, char* __restrict__ ws) {
    int idx = blockIdx.x * 256 + threadIdx.x;
    unsigned short* we1t = (unsigned short*)(ws + OFF_WE1T);
    unsigned short* wa1t = (unsigned short*)(ws + OFF_WA1T);
    unsigned short* we2t = (unsigned short*)(ws + OFF_WE2T);
    unsigned short* wn1t = (unsigned short*)(ws + OFF_WN1T);
    unsigned short* wn2t = (unsigned short*)(ws + OFF_WN2T);
    if (idx < 128 * 192) {
        int n = idx / 192, k = idx % 192;
        we1t[idx] = bf16s(We1[k * 128 + n]);
        wa1t[idx] = bf16s(Wa1[k * 128 + n]);
    }
    if (idx < 64 * 128) {
        int n = idx / 128, k = idx % 128;
        we2t[idx] = bf16s(We2[k * 64 + n]);
        wn2t[idx] = bf16s(Wn2[k * 64 + n]);
    }
    if (idx < 128 * 128) {
        int n = idx / 128, k = idx % 128;
        wn1t[idx] = bf16s(Wn1[k * 128 + n]);
    }
}

// ---- K1: edge MLP (uef + logits + segment-max), 128 edges / 256-thread block ----
// 32x32x16 MFMA; A-frags prefetched from global; weights staged per K=32 chunk.
__global__ __launch_bounds__(256, 2) void k1_edge(
    const float* __restrict__ nf, const float* __restrict__ ef,
    const float* __restrict__ be1, const float* __restrict__ be2,
    const float* __restrict__ ba1, const float* __restrict__ Wa2,
    const float* __restrict__ ba2, const int* __restrict__ src,
    const int* __restrict__ dst, char* __restrict__ ws,
    float* __restrict__ uef_out) {
    __shared__ __align__(16) unsigned short sW[2 * 128 * 40];  // K-chunk of We1T/Wa1T; reused for We2T [64][136]
    __shared__ __align__(16) unsigned short sH[128 * 136];     // H1e bf16

    const int tid = threadIdx.x;
    const int wv = tid >> 6;
    const int l = tid & 63;
    const int m32 = l & 31;
    const int half = l >> 5;
    const long ebase = (long)blockIdx.x * 128;
    const long erow = ebase + wv * 32 + m32;
    const int sa = src[erow], da = dst[erow];

    const unsigned short* __restrict__ We1T = (const unsigned short*)(ws + OFF_WE1T);
    const unsigned short* __restrict__ Wa1T = (const unsigned short*)(ws + OFF_WA1T);
    const unsigned short* __restrict__ We2T = (const unsigned short*)(ws + OFF_WE2T);

    // ---- prefetch entire A row (192 floats' worth per lane-half) and convert to bf16 ----
    short8 A[12];
    {
        const float* __restrict__ pe = ef + erow * 64;
        const float* __restrict__ ps = nf + (long)sa * 64;
        const float* __restrict__ pd = nf + (long)da * 64;
#pragma unroll
        for (int seg = 0; seg < 3; ++seg) {
            const float* p = (seg == 0 ? pe : (seg == 1 ? ps : pd));
#pragma unroll
            for (int t = 0; t < 4; ++t) {
                f32x4 v0 = *(const f32x4*)(p + t * 16 + half * 8);
                f32x4 v1 = *(const f32x4*)(p + t * 16 + half * 8 + 4);
                short8 a;
#pragma unroll
                for (int j = 0; j < 4; ++j) {
                    a[j] = (short)bf16s(v0[j]);
                    a[4 + j] = (short)bf16s(v1[j]);
                }
                A[seg * 4 + t] = a;
            }
        }
    }

    f32x16 accE[4], accA[4];
#pragma unroll
    for (int i = 0; i < 4; ++i) {
#pragma unroll
        for (int j = 0; j < 16; ++j) { accE[i][j] = 0.f; accA[i][j] = 0.f; }
    }

    // ---- GEMM1: [128e x 192] @ (We1T | Wa1T) -> two [128e x 128] accumulators ----
#pragma unroll
    for (int kk = 0; kk < 6; ++kk) {
#pragma unroll
        for (int c = 0; c < 4; ++c) {
            int ci = tid + c * 256;            // 0..1023 chunks of 8 shorts
            int mat = ci >> 9;
            int r = (ci >> 2) & 127;
            int c8 = (ci & 3) << 3;
            *(short8*)&sW[mat * 5120 + r * 40 + c8] =
                *(const short8*)((mat ? Wa1T : We1T) + r * 192 + kk * 32 + c8);
        }
        __syncthreads();
#pragma unroll
        for (int ks = 0; ks < 2; ++ks) {
            short8 a = A[kk * 2 + ks];
#pragma unroll
            for (int nt = 0; nt < 4; ++nt) {
                const int bo = (nt * 32 + m32) * 40 + ks * 16 + half * 8;
                short8 b0 = *(const short8*)&sW[bo];
                short8 b1 = *(const short8*)&sW[5120 + bo];
                accE[nt] = MFMA32(a, b0, accE[nt]);
                accA[nt] = MFMA32(a, b1, accA[nt]);
            }
        }
        __syncthreads();
    }

    // ---- attention head: logit = ReLU(h1a+ba1).Wa2 + ba2, reduce across 32 lanes ----
    {
        float ba1v[4], wa2v[4];
#pragma unroll
        for (int nt = 0; nt < 4; ++nt) {
            int cc = nt * 32 + m32;
            ba1v[nt] = ba1[cc];
            wa2v[nt] = Wa2[cc];
        }
        float lg[16];
#pragma unroll
        for (int r = 0; r < 16; ++r) {
            float p = 0.f;
#pragma unroll
            for (int nt = 0; nt < 4; ++nt)
                p += fmaxf(accA[nt][r] + ba1v[nt], 0.f) * wa2v[nt];
            lg[r] = p;
        }
#pragma unroll
        for (int mk = 1; mk < 32; mk <<= 1) {
#pragma unroll
            for (int r = 0; r < 16; ++r) lg[r] += __shfl_xor(lg[r], mk, 64);
        }
        if (m32 == 0) {
            float bb2 = ba2[0];
            float* logits = (float*)(ws + OFF_LOGIT);
            unsigned* segmaxu = (unsigned*)(ws + OFF_SEGMAXU);
#pragma unroll
            for (int r = 0; r < 16; ++r) {
                long er = ebase + wv * 32 + (r & 3) + 8 * (r >> 2) + 4 * half;
                float v = lg[r] + bb2;
                logits[er] = v;
                atomicMax(&segmaxu[dst[er]], fkey(v));
            }
        }
    }

    // ---- H1e = ReLU(accE + be1) -> sH (C-layout scatter) ----
#pragma unroll
    for (int nt = 0; nt < 4; ++nt) {
        int cc = nt * 32 + m32;
        float bb = be1[cc];
#pragma unroll
        for (int r = 0; r < 16; ++r) {
            int rowl = wv * 32 + (r & 3) + 8 * (r >> 2) + 4 * half;
            sH[rowl * 136 + cc] = bf16s(fmaxf(accE[nt][r] + bb, 0.f));
        }
    }
    // stage We2T [64n][128k] -> sW (stride 136)
#pragma unroll
    for (int c = 0; c < 4; ++c) {
        int ci = tid + c * 256;
        int r = ci >> 4;
        int c8 = (ci & 15) << 3;
        *(short8*)&sW[r * 136 + c8] = *(const short8*)(We2T + r * 128 + c8);
    }
    __syncthreads();

    // ---- GEMM2: H[128e x 128] @ We2T -> uef [128e x 64] ----
    f32x16 acc2[2];
#pragma unroll
    for (int i = 0; i < 2; ++i) {
#pragma unroll
        for (int j = 0; j < 16; ++j) acc2[i][j] = 0.f;
    }
#pragma unroll
    for (int s = 0; s < 8; ++s) {
        short8 a2 = *(const short8*)&sH[(wv * 32 + m32) * 136 + s * 16 + half * 8];
#pragma unroll
        for (int nt = 0; nt < 2; ++nt) {
            short8 b = *(const short8*)&sW[(nt * 32 + m32) * 136 + s * 16 + half * 8];
            acc2[nt] = MFMA32(a2, b, acc2[nt]);
        }
    }
#pragma unroll
    for (int nt = 0; nt < 2; ++nt) {
        int cc = nt * 32 + m32;
        float bb = be2[cc];
#pragma unroll
        for (int r = 0; r < 16; ++r) {
            long er = ebase + wv * 32 + (r & 3) + 8 * (r >> 2) + 4 * half;
            uef_out[er * 64 + cc] = acc2[nt][r] + bb;
        }
    }
}

// ---- K2: edge-parallel exp + UNNORMALIZED weighted scatter (replaces khist/kscan/k2/k3) ----
// One wave per edge: lane c handles column c. uef read is COALESCED (256B/edge in edge
// order); the scatter is 64 f32 atomics into agg[dst] plus segsum/cnt (one lane each).
// Normalization by 1/(segsum*cnt) is deferred to k4.
__global__ __launch_bounds__(256) void k2_scatter(const int* __restrict__ dst,
                                                  char* __restrict__ ws,
                                                  const float* __restrict__ uef) {
    const int tid = threadIdx.x;
    const long e = (long)blockIdx.x * 4 + (tid >> 6);
    const int c = tid & 63;
    const float* logits = (const float*)(ws + OFF_LOGIT);
    const unsigned* segmaxu = (const unsigned*)(ws + OFF_SEGMAXU);
    float* segsum = (float*)(ws + OFF_SEGSUM);
    int* cnti = (int*)(ws + OFF_CNTI);
    float* agg = (float*)(ws + OFF_AGG);
    const int d = dst[e];
    const float ev = __expf(logits[e] - funkey(segmaxu[d]));
    if (c == 0) atomicAdd(&segsum[d], ev);
    if (c == 1) atomicAdd(&cnti[d], 1);
    atomicAdd(&agg[(long)d * 64 + c], ev * uef[e * 64 + c]);
}

// ---- K4: node MLP on [agg_m | nf]; folds 1/(segsum*cnt) into the bf16 A-frag ----
__global__ __launch_bounds__(256) void k4_node(
    const float* __restrict__ nf, const float* __restrict__ bn1,
    const float* __restrict__ bn2, char* __restrict__ ws,
    float* __restrict__ unf_out) {
    __shared__ __align__(16) unsigned short sW[8704];
    __shared__ __align__(16) unsigned short sH[64 * 136];

    const int tid = threadIdx.x;
    const int wv = tid >> 6;
    const int lane = tid & 63;
    const int c16 = lane & 15;
    const int quad = lane >> 4;
    const int nbase = blockIdx.x * 64;
    int node = nbase + wv * 16 + c16;
    int nodec = min(node, NN - 1);

    const float* agg = (const float*)(ws + OFF_AGG);
    const float* segsum = (const float*)(ws + OFF_SEGSUM);
    const int* cnti = (const int*)(ws + OFF_CNTI);
    const unsigned short* Wn1T = (const unsigned short*)(ws + OFF_WN1T);
    const unsigned short* Wn2T = (const unsigned short*)(ws + OFF_WN2T);
    const float* __restrict__ pa = agg + (long)nodec * 64;
    const float* __restrict__ pn = nf + (long)nodec * 64;

    float sc = 0.f;
    {
        int ct = cnti[nodec];
        if (ct > 0) sc = 1.f / (segsum[nodec] * (float)ct);
    }

    f32x4 acc[8];
#pragma unroll
    for (int i = 0; i < 8; ++i) acc[i] = (f32x4){0, 0, 0, 0};

#pragma unroll
    for (int kk = 0; kk < 4; ++kk) {
#pragma unroll
        for (int c = 0; c < 2; ++c) {
            int ci = tid + c * 256;
            int r = ci >> 2;
            int c8 = (ci & 3) << 3;
            *(short8*)&sW[r * 40 + c8] = *(const short8*)(Wn1T + r * 128 + kk * 32 + c8);
        }
        __syncthreads();
        const float* p = (kk < 2 ? pa : pn) + (kk & 1) * 32 + quad * 8;
        const float m = (kk < 2) ? sc : 1.f;
        f32x4 f0 = *(const f32x4*)p;
        f32x4 f1 = *(const f32x4*)(p + 4);
        short8 a;
#pragma unroll
        for (int i = 0; i < 4; ++i) {
            a[i] = (short)bf16s(f0[i] * m);
            a[4 + i] = (short)bf16s(f1[i] * m);
        }
#pragma unroll
        for (int nt = 0; nt < 8; ++nt) {
            short8 b = *(const short8*)&sW[(nt * 16 + c16) * 40 + quad * 8];
            acc[nt] = MFMA16(a, b, acc[nt]);
        }
        __syncthreads();
    }

#pragma unroll
    for (int nt = 0; nt < 8; ++nt) {
        int cc = nt * 16 + c16;
        float bb = bn1[cc];
#pragma unroll
        for (int r = 0; r < 4; ++r) {
            float h = fmaxf(acc[nt][r] + bb, 0.f);
            sH[(wv * 16 + quad * 4 + r) * 136 + cc] = bf16s(h);
        }
    }
#pragma unroll
    for (int c = 0; c < 4; ++c) {
        int ci = tid + c * 256;
        int r = ci >> 4;
        int c8 = (ci & 15) << 3;
        *(short8*)&sW[r * 136 + c8] = *(const short8*)(Wn2T + r * 128 + c8);
    }
    __syncthreads();

    f32x4 acc2[4];
#pragma unroll
    for (int i = 0; i < 4; ++i) acc2[i] = (f32x4){0, 0, 0, 0};
#pragma unroll
    for (int kk = 0; kk < 4; ++kk) {
        short8 a2 = *(const short8*)&sH[(wv * 16 + c16) * 136 + kk * 32 + quad * 8];
#pragma unroll
        for (int nt = 0; nt < 4; ++nt) {
            short8 b = *(const short8*)&sW[(nt * 16 + c16) * 136 + kk * 32 + quad * 8];
            acc2[nt] = MFMA16(a2, b, acc2[nt]);
        }
    }
#pragma unroll
    for (int nt = 0; nt < 4; ++nt) {
        int cc = nt * 16 + c16;
        float bb = bn2[cc];
#pragma unroll
        for (int r = 0; r < 4; ++r) {
            int nrow = nbase + wv * 16 + quad * 4 + r;
            if (nrow < NN) unf_out[(long)nrow * 64 + cc] = acc2[nt][r] + bb;
        }
    }
}

extern "C" void kernel_launch(void* const* d_in, const int* in_sizes, int n_in,
                              void* d_out, int out_size, void* d_ws, size_t ws_size,
                              hipStream_t stream) {
    const float* nf  = (const float*)d_in[0];
    const float* ef  = (const float*)d_in[1];
    const float* We1 = (const float*)d_in[2];
    const float* be1 = (const float*)d_in[3];
    const float* We2 = (const float*)d_in[4];
    const float* be2 = (const float*)d_in[5];
    const float* Wa1 = (const float*)d_in[6];
    const float* ba1 = (const float*)d_in[7];
    const float* Wa2 = (const float*)d_in[8];
    const float* ba2 = (const float*)d_in[9];
    const float* Wn1 = (const float*)d_in[10];
    const float* bn1 = (const float*)d_in[11];
    const float* Wn2 = (const float*)d_in[12];
    const float* bn2 = (const float*)d_in[13];
    const int* src = (const int*)d_in[14];
    const int* dst = (const int*)d_in[15];
    char* ws = (char*)d_ws;
    float* unf_out = (float*)d_out;                       // [N,64] first
    float* uef_out = (float*)d_out + (size_t)NN * 64;     // then [E,64]

    // zero segmaxu|segsum|cnti|agg (contiguous)
    hipMemsetAsync(ws + OFF_SEGMAXU, 0, (size_t)NN * 12 + (size_t)NN * 256, stream);
    k0_init<<<96, 256, 0, stream>>>(We1, Wa1, We2, Wn1, Wn2, ws);
    k1_edge<<<E_EDGES / 128, 256, 0, stream>>>(nf, ef, be1, be2, ba1, Wa2, ba2, src, dst, ws, uef_out);
    k2_scatter<<<E_EDGES / 4, 256, 0, stream>>>(dst, ws, uef_out);
    k4_node<<<(NN + 63) / 64, 256, 0, stream>>>(nf, bn1, bn2, ws, unf_out);
}